// Round 1
// baseline (2860.734 us; speedup 1.0000x reference)
//
#include <hip/hip_runtime.h>
#include <hip/hip_bf16.h>

// ---------------------------------------------------------------------------
// SovarielOmega fused net, fp32 baseline.
// B=2048, S=8, RAW=1024, E=512, H=256, NH=8
// ---------------------------------------------------------------------------

#define ROWS   16384      // B*S
#define BATCH  2048
#define SEQL   8
#define HID    256
#define EMB    512

// ---- workspace layout (in floats) ----
// 0        .. 8M   : M1A (mlp1 audio out 16384x512)   -> later LSTM1 (16384x512)
// 8M       .. 16M  : M1V (mlp1 visual out)            -> later LSTM2
// 16M      .. 24M  : SEQ (16384x512)                  -> later QKV part (16M..40M)
// 24M      .. 56M  : PRE (2 x 16384x1024)             -> later CTX(40..48M), AOUT(48..56M)
// 56M      .. 60M  : GBUF (2 x 2048x1024)             -> later SUMM/COLSUM/WTS/WC1T
// 60M      .. 63M  : H0, H1, CBUF (each 2x2048x256)
static const size_t F_M1A  = 0;
static const size_t F_M1V  = 8388608;
static const size_t F_SEQ  = 16777216;
static const size_t F_PRE  = 25165824;      // 2*16384*1024 = 33554432
static const size_t F_GBUF = 58720256;      // 2*2048*1024  = 4194304
static const size_t F_H0   = 62914560;      // 2*2048*256   = 1048576
static const size_t F_H1   = F_H0 + 1048576;
static const size_t F_CB   = F_H1 + 1048576;
// reuse regions
static const size_t F_LSTM1 = F_M1A;
static const size_t F_LSTM2 = F_M1V;
static const size_t F_QKV   = F_SEQ;          // 16384*1536 = 25165824 floats (16M..40M)
static const size_t F_CTX   = 41943040;       // 8M floats
static const size_t F_AOUT  = 50331648;       // 8M floats
static const size_t F_SUMM   = F_GBUF;              // 2048*512
static const size_t F_COLSUM = F_GBUF + 1048576;    // 2048*8*8
static const size_t F_WTS    = F_COLSUM + 131072;   // 2048*8
static const size_t F_WC1T   = F_WTS + 16384;       // 513*256

#define TBM 64
#define TBN 64
#define TBK 16

// C[m, coloff+n] = act( A[m,:]·W[n,:] + b1[n] + b2[n] + D[m,n] )
// blockIdx.z selects variant via element strides sA/sW/sb1/sb2/sD/sC.
__global__ __launch_bounds__(256) void gemm_f32(
    const float* __restrict__ A, long long sA,
    const float* __restrict__ W, long long sW,
    const float* __restrict__ b1, long long sb1,
    const float* __restrict__ b2, long long sb2,
    const float* __restrict__ D, long long sD, int ldd,
    float* __restrict__ C, long long sC,
    int M, int N, int K, int ldc, int coloff, int do_relu)
{
    const int z = blockIdx.z;
    A += (long long)z * sA;
    W += (long long)z * sW;
    C += (long long)z * sC;
    if (b1) b1 += (long long)z * sb1;
    if (b2) b2 += (long long)z * sb2;
    if (D)  D  += (long long)z * sD;

    __shared__ float As[TBK][TBM + 4];
    __shared__ float Ws[TBK][TBN + 4];

    const int tid = threadIdx.x;
    const int tm = tid >> 4;          // 0..15
    const int tn = tid & 15;          // 0..15
    const long long m0 = (long long)blockIdx.x * TBM;
    const long long n0 = (long long)blockIdx.y * TBN;

    const int lr = tid >> 2;          // 0..63 tile row
    const int lk = (tid & 3) * 4;     // 0,4,8,12

    float acc[4][4] = {};

    const float* Ap = A + (m0 + lr) * K + lk;
    const float* Wp = W + (n0 + lr) * K + lk;

    for (int k0 = 0; k0 < K; k0 += TBK) {
        float4 av = *(const float4*)(Ap + k0);
        float4 wv = *(const float4*)(Wp + k0);
        As[lk+0][lr] = av.x; As[lk+1][lr] = av.y; As[lk+2][lr] = av.z; As[lk+3][lr] = av.w;
        Ws[lk+0][lr] = wv.x; Ws[lk+1][lr] = wv.y; Ws[lk+2][lr] = wv.z; Ws[lk+3][lr] = wv.w;
        __syncthreads();
#pragma unroll
        for (int k = 0; k < TBK; ++k) {
            float4 a = *(const float4*)&As[k][tm * 4];
            float4 w = *(const float4*)&Ws[k][tn * 4];
            acc[0][0] += a.x*w.x; acc[0][1] += a.x*w.y; acc[0][2] += a.x*w.z; acc[0][3] += a.x*w.w;
            acc[1][0] += a.y*w.x; acc[1][1] += a.y*w.y; acc[1][2] += a.y*w.z; acc[1][3] += a.y*w.w;
            acc[2][0] += a.z*w.x; acc[2][1] += a.z*w.y; acc[2][2] += a.z*w.z; acc[2][3] += a.z*w.w;
            acc[3][0] += a.w*w.x; acc[3][1] += a.w*w.y; acc[3][2] += a.w*w.z; acc[3][3] += a.w*w.w;
        }
        __syncthreads();
    }

    const long long mb = m0 + tm * 4;
    const long long nb = n0 + tn * 4;
    float bias[4] = {0.f, 0.f, 0.f, 0.f};
    if (b1) {
#pragma unroll
        for (int j = 0; j < 4; ++j) bias[j] += b1[nb + j];
    }
    if (b2) {
#pragma unroll
        for (int j = 0; j < 4; ++j) bias[j] += b2[nb + j];
    }
#pragma unroll
    for (int i = 0; i < 4; ++i) {
#pragma unroll
        for (int j = 0; j < 4; ++j) {
            float v = acc[i][j] + bias[j];
            if (D) v += D[(mb + i) * (long long)ldd + nb + j];
            if (do_relu) v = fmaxf(v, 0.f);
            C[(mb + i) * (long long)ldc + coloff + nb + j] = v;
        }
    }
}

__device__ __forceinline__ float sigf(float x) { return 1.f / (1.f + expf(-x)); }

// 2*2048*256 threads: d = dir, b = batch, n = hidden idx
__global__ __launch_bounds__(256) void lstm_gates(
    const float* __restrict__ src,   // first: PRE (dir stride 16384*1024); else GBUF (dir stride 2048*1024)
    float* __restrict__ cbuf,        // (2,2048,256)
    float* __restrict__ hout,        // (2,2048,256)
    float* __restrict__ lout,        // (16384,512): fwd cols 0..255, bwd 256..511
    int t, int first)
{
    const int gid = blockIdx.x * 256 + threadIdx.x;
    const int d = gid >> 19;
    const int r = gid & ((1 << 19) - 1);
    const int b = r >> 8;
    const int n = r & 255;
    const int te = d ? (7 - t) : t;

    const float* row;
    if (first) row = src + (size_t)d * 16384 * 1024 + ((size_t)b * 8 + te) * 1024;
    else       row = src + (size_t)d * 2048 * 1024 + (size_t)b * 1024;

    const float ig = row[n];
    const float fg = row[n + 256];
    const float gg = row[n + 512];
    const float og = row[n + 768];
    const float cp = first ? 0.f : cbuf[gid];

    const float c = sigf(fg) * cp + sigf(ig) * tanhf(gg);
    const float h = sigf(og) * tanhf(c);

    cbuf[gid] = c;
    hout[gid] = h;
    lout[((size_t)b * 8 + te) * 512 + d * 256 + n] = h;
}

// one wave per (b, head)
__global__ __launch_bounds__(64) void attn_kernel(
    const float* __restrict__ qkv,   // (16384, 1536)
    float* __restrict__ ctx,         // (16384, 512)
    float* __restrict__ colsum)      // (2048, 8, 8): sum over q of P[q][k]
{
    const int bh = blockIdx.x;
    const int b = bh >> 3;
    const int h = bh & 7;
    const int t = threadIdx.x;

    __shared__ float q[8][64], k[8][64], v[8][64], p[8][8];
    const float* base = qkv + (size_t)b * 8 * 1536 + h * 64;
#pragma unroll
    for (int s = 0; s < 8; ++s) {
        q[s][t] = base[s * 1536 + t];
        k[s][t] = base[s * 1536 + 512 + t];
        v[s][t] = base[s * 1536 + 1024 + t];
    }
    __syncthreads();

    const int qi = t >> 3;
    const int kj = t & 7;
    float sc = 0.f;
#pragma unroll
    for (int d = 0; d < 64; ++d) sc += q[qi][d] * k[kj][d];
    sc *= 0.125f;

    float mx = sc;
    for (int off = 1; off < 8; off <<= 1) mx = fmaxf(mx, __shfl_xor(mx, off));
    const float e = expf(sc - mx);
    float sum = e;
    for (int off = 1; off < 8; off <<= 1) sum += __shfl_xor(sum, off);
    const float P = e / sum;
    p[qi][kj] = P;

    float cs = P;
    for (int off = 8; off < 64; off <<= 1) cs += __shfl_xor(cs, off);
    if (t < 8) colsum[(size_t)bh * 8 + t] = cs;
    __syncthreads();

    float* cb = ctx + ((size_t)b * 8 + qi) * 512 + h * 64;
#pragma unroll
    for (int j = 0; j < 8; ++j) {
        const int d = (t & 7) + 8 * j;
        float o = 0.f;
#pragma unroll
        for (int kk = 0; kk < 8; ++kk) o += p[qi][kk] * v[kk][d];
        cb[d] = o;
    }
}

// weights[b,k] = softmax_k( (1/64) * sum_h colsum[b,h,k] ) ; 8 b's per 64-thread block
__global__ __launch_bounds__(64) void weights_kernel(
    const float* __restrict__ colsum, float* __restrict__ wts)
{
    const int t = threadIdx.x;
    const int b = blockIdx.x * 8 + (t >> 3);
    const int kk = t & 7;
    const float* cs = colsum + (size_t)b * 64;
    float s = 0.f;
#pragma unroll
    for (int h = 0; h < 8; ++h) s += cs[h * 8 + kk];
    s *= (1.f / 64.f);
    float mx = s;
    for (int off = 1; off < 8; off <<= 1) mx = fmaxf(mx, __shfl_xor(mx, off));
    const float e = expf(s - mx);
    float sum = e;
    for (int off = 1; off < 8; off <<= 1) sum += __shfl_xor(sum, off);
    wts[(size_t)b * 8 + kk] = e / sum;
}

// summary[b,e] = sum_s aout[b,s,e] * wts[b,s]
__global__ __launch_bounds__(256) void summary_kernel(
    const float* __restrict__ aout, const float* __restrict__ wts,
    float* __restrict__ summ)
{
    const int gid = blockIdx.x * 256 + threadIdx.x;   // 2048*512
    const int b = gid >> 9;
    const int e = gid & 511;
    const float* ab = aout + (size_t)b * 8 * 512 + e;
    const float* wb = wts + (size_t)b * 8;
    float s = 0.f;
#pragma unroll
    for (int t = 0; t < 8; ++t) s += ab[t * 512] * wb[t];
    summ[gid] = s;
}

__global__ __launch_bounds__(256) void transpose_wc1(
    const float* __restrict__ Wc1, float* __restrict__ Wc1T)
{
    const int gid = blockIdx.x * 256 + threadIdx.x;   // 256*513
    const int j = gid / 513;
    const int e = gid % 513;
    Wc1T[(size_t)e * 256 + j] = Wc1[gid];
}

// per-b: hidden = relu(summ·Wc1T + bc1); out = min(sigmoid(hidden·Wc2 + bc2), CEIL)
__global__ __launch_bounds__(256) void coherence_kernel(
    const float* __restrict__ summ, const float* __restrict__ Wc1T,
    const float* __restrict__ bc1, const float* __restrict__ Wc2,
    const float* __restrict__ bc2, float* __restrict__ out)
{
    const int b = blockIdx.x;
    const int j = threadIdx.x;
    __shared__ float s[512];
    __shared__ float red[4];
    s[j]       = summ[(size_t)b * 512 + j];
    s[j + 256] = summ[(size_t)b * 512 + 256 + j];
    __syncthreads();

    float hj = bc1[j];
    for (int e = 0; e < 512; ++e) hj += s[e] * Wc1T[(size_t)e * 256 + j];
    hj = fmaxf(hj, 0.f);
    float val = hj * Wc2[j];
    for (int off = 1; off < 64; off <<= 1) val += __shfl_xor(val, off);
    if ((j & 63) == 0) red[j >> 6] = val;
    __syncthreads();
    if (j == 0) {
        const float tot = red[0] + red[1] + red[2] + red[3] + bc2[0];
        const float c = 1.f / (1.f + expf(-tot));
        out[b] = fminf(c, 0.9998f);
    }
}

extern "C" void kernel_launch(void* const* d_in, const int* in_sizes, int n_in,
                              void* d_out, int out_size, void* d_ws, size_t ws_size,
                              hipStream_t stream)
{
    (void)in_sizes; (void)n_in; (void)out_size; (void)ws_size;

    const float* audio  = (const float*)d_in[0];
    const float* visual = (const float*)d_in[1];
    const float* Wa1 = (const float*)d_in[2];  const float* ba1 = (const float*)d_in[3];
    const float* Wa2 = (const float*)d_in[4];  const float* ba2 = (const float*)d_in[5];
    const float* Wv1 = (const float*)d_in[6];  const float* bv1 = (const float*)d_in[7];
    const float* Wv2 = (const float*)d_in[8];  const float* bv2 = (const float*)d_in[9];
    const float* Wih = (const float*)d_in[10]; const float* Whh = (const float*)d_in[11];
    const float* bih = (const float*)d_in[12]; const float* bhh = (const float*)d_in[13];
    const float* Wqkv = (const float*)d_in[14]; const float* bqkv = (const float*)d_in[15];
    const float* Wo  = (const float*)d_in[16]; const float* bo  = (const float*)d_in[17];
    const float* Wc1 = (const float*)d_in[18]; const float* bc1 = (const float*)d_in[19];
    const float* Wc2 = (const float*)d_in[20]; const float* bc2 = (const float*)d_in[21];

    float* ws  = (float*)d_ws;
    float* out = (float*)d_out;

    float* M1A  = ws + F_M1A;
    float* M1V  = ws + F_M1V;
    float* SEQ  = ws + F_SEQ;
    float* PRE  = ws + F_PRE;
    float* GBUF = ws + F_GBUF;
    float* H0   = ws + F_H0;
    float* H1   = ws + F_H1;
    float* CB   = ws + F_CB;
    float* LSTM1 = ws + F_LSTM1;
    float* LSTM2 = ws + F_LSTM2;
    float* QKV  = ws + F_QKV;
    float* CTX  = ws + F_CTX;
    float* AOUT = ws + F_AOUT;
    float* SUMM = ws + F_SUMM;
    float* COLSUM = ws + F_COLSUM;
    float* WTS  = ws + F_WTS;
    float* WC1T = ws + F_WC1T;

    const dim3 blk(256);
    auto gemm = [&](const float* A, long long sA, const float* W, long long sW,
                    const float* b1, long long sb1, const float* b2, long long sb2,
                    const float* D, long long sD, int ldd,
                    float* C, long long sC,
                    int M, int N, int K, int ldc, int coloff, int relu, int nz) {
        dim3 grid(M / TBM, N / TBN, nz);
        hipLaunchKernelGGL(gemm_f32, grid, blk, 0, stream,
                           A, sA, W, sW, b1, sb1, b2, sb2, D, sD, ldd,
                           C, sC, M, N, K, ldc, coloff, relu);
    };

    // --- modality MLPs ---
    gemm(audio,  0, Wa1, 0, ba1, 0, nullptr, 0, nullptr, 0, 0, M1A, 0, ROWS, 512, 1024, 512, 0,   1, 1);
    gemm(visual, 0, Wv1, 0, bv1, 0, nullptr, 0, nullptr, 0, 0, M1V, 0, ROWS, 512, 1024, 512, 0,   1, 1);
    gemm(M1A, 0, Wa2, 0, ba2, 0, nullptr, 0, nullptr, 0, 0, SEQ, 0, ROWS, 256, 512, 512, 0,   0, 1);
    gemm(M1V, 0, Wv2, 0, bv2, 0, nullptr, 0, nullptr, 0, 0, SEQ, 0, ROWS, 256, 512, 512, 256, 0, 1);

    // --- BiLSTM, 2 layers ---
    for (int l = 0; l < 2; ++l) {
        const float* xin  = (l == 0) ? SEQ : LSTM1;
        float* lout       = (l == 0) ? LSTM1 : LSTM2;
        const float* Wih_l = Wih + (size_t)l * 2 * 1024 * 512;
        const float* Whh_l = Whh + (size_t)l * 2 * 1024 * 256;
        const float* bih_l = bih + (size_t)l * 2 * 1024;
        const float* bhh_l = bhh + (size_t)l * 2 * 1024;

        // input projection (both dirs via z)
        gemm(xin, 0, Wih_l, 1024LL * 512, bih_l, 1024, bhh_l, 1024,
             nullptr, 0, 0, PRE, 16384LL * 1024, ROWS, 1024, 512, 1024, 0, 0, 2);

        for (int t = 0; t < 8; ++t) {
            if (t > 0) {
                const float* hin = (t & 1) ? H1 : H0;
                const float* Dp = PRE + (size_t)t * 1024;           // z=0 time offset
                long long sD = 16384LL * 1024 + (long long)(7 - 2 * t) * 1024;  // z=1: +(7-t)*1024
                gemm(hin, 2048LL * 256, Whh_l, 1024LL * 256,
                     nullptr, 0, nullptr, 0,
                     Dp, sD, 8192,
                     GBUF, 2048LL * 1024, BATCH, 1024, 256, 1024, 0, 0, 2);
            }
            float* hout = ((t + 1) & 1) ? H1 : H0;
            const float* src = (t == 0) ? (const float*)PRE : (const float*)GBUF;
            hipLaunchKernelGGL(lstm_gates, dim3(4096), blk, 0, stream,
                               src, CB, hout, lout, t, (int)(t == 0));
        }
    }

    // --- MHA ---
    gemm(LSTM2, 0, Wqkv, 0, bqkv, 0, nullptr, 0, nullptr, 0, 0, QKV, 0, ROWS, 1536, 512, 1536, 0, 0, 1);
    hipLaunchKernelGGL(attn_kernel, dim3(BATCH * 8), dim3(64), 0, stream, QKV, CTX, COLSUM);
    hipLaunchKernelGGL(weights_kernel, dim3(BATCH / 8), dim3(64), 0, stream, COLSUM, WTS);
    gemm(CTX, 0, Wo, 0, bo, 0, nullptr, 0, nullptr, 0, 0, AOUT, 0, ROWS, 512, 512, 512, 0, 0, 1);

    // --- pooling + head ---
    hipLaunchKernelGGL(summary_kernel, dim3(BATCH * 512 / 256), blk, 0, stream, AOUT, WTS, SUMM);
    hipLaunchKernelGGL(transpose_wc1, dim3(513), blk, 0, stream, Wc1, WC1T);
    hipLaunchKernelGGL(coherence_kernel, dim3(BATCH), blk, 0, stream, SUMM, WC1T, bc1, Wc2, bc2, out);
}

// Round 2
// 1080.631 us; speedup vs baseline: 2.6473x; 2.6473x over previous
//
#include <hip/hip_runtime.h>
#include <hip/hip_bf16.h>

// ---------------------------------------------------------------------------
// SovarielOmega fused net — round 1: bf16 MFMA GEMMs (m97-style 128x128 tile).
// B=2048, S=8, RAW=1024, E=512, H=256, NH=8
// ---------------------------------------------------------------------------

#define ROWS   16384      // B*S
#define BATCH  2048

typedef __bf16 bf16x8 __attribute__((ext_vector_type(8)));
typedef float  f32x4  __attribute__((ext_vector_type(4)));

typedef __hip_bfloat16 bf16;

// ---- workspace layout (byte offsets, MiB-granular) ----
// 0   ..12  : weights bf16 (10.5 used)
// 12  ..44  : audio bf16 (32)      -> later QKV fp32 (12..108) -> later AOUT fp32 (12..44)
// 44  ..76  : visual bf16 (32)
// 76  ..92  : M1A bf16 (16)
// 92  ..108 : M1V bf16 (16)
// 108 ..124 : SEQ bf16 (16)        -> later CTX bf16 (16)
// 124 ..188 : PRE bf16 (64)  [2 x 16384 x 1024]
// 188 ..204 : GBUF fp32 (16) [2 x 2048 x 1024]
// 204 ..206 : H bf16 (2)     [2 x 2048 x 256]
// 206 ..210 : CB fp32 (4)
// 210 ..226 : LSTM1 bf16 (16)
// 226 ..242 : LSTM2 bf16 (16)
// 242 ..    : COLSUM, WTS, SUMM, WC1T
#define MB(x) ((size_t)(x) << 20)
static const size_t OFF_WB    = 0;
static const size_t OFF_ABF   = MB(12);
static const size_t OFF_VBF   = MB(44);
static const size_t OFF_M1A   = MB(76);
static const size_t OFF_M1V   = MB(92);
static const size_t OFF_SEQ   = MB(108);
static const size_t OFF_PRE   = MB(124);
static const size_t OFF_GBUF  = MB(188);
static const size_t OFF_H     = MB(204);
static const size_t OFF_CB    = MB(206);
static const size_t OFF_LSTM1 = MB(210);
static const size_t OFF_LSTM2 = MB(226);
static const size_t OFF_QKV   = MB(12);     // reuse (audio/visual/M1A dead)
static const size_t OFF_CTX   = MB(108);    // reuse SEQ
static const size_t OFF_AOUT  = MB(12);     // reuse QKV
static const size_t OFF_COLSUM= MB(242);
static const size_t OFF_WTS   = MB(243);
static const size_t OFF_SUMM  = MB(244);
static const size_t OFF_WC1T  = MB(248);

// weight bf16 element offsets within OFF_WB
static const size_t WB_WA1  = 0;         // 524288
static const size_t WB_WV1  = 524288;    // 524288
static const size_t WB_WA2  = 1048576;   // 131072
static const size_t WB_WV2  = 1179648;   // 131072
static const size_t WB_WIH  = 1310720;   // 2097152
static const size_t WB_WHH  = 3407872;   // 1048576
static const size_t WB_WQKV = 4456448;   // 786432
static const size_t WB_WO   = 5242880;   // 262144

// ---------------------------------------------------------------------------
// batched fp32 -> bf16 convert
// ---------------------------------------------------------------------------
struct ConvJobs {
    const float* src[10];
    bf16*        dst[10];
    long long    cum[11];   // cumulative float4-group counts
};

__global__ __launch_bounds__(256) void convert_bf16(ConvJobs jobs, long long total4)
{
    for (long long g = (long long)blockIdx.x * 256 + threadIdx.x; g < total4;
         g += (long long)gridDim.x * 256) {
        int j = 0;
        while (g >= jobs.cum[j + 1]) ++j;
        const long long idx = g - jobs.cum[j];
        const float4 v = ((const float4*)jobs.src[j])[idx];
        union { ushort4 u; bf16 h[4]; } p;
        p.h[0] = __float2bfloat16(v.x);
        p.h[1] = __float2bfloat16(v.y);
        p.h[2] = __float2bfloat16(v.z);
        p.h[3] = __float2bfloat16(v.w);
        ((ushort4*)jobs.dst[j])[idx] = p.u;
    }
}

// ---------------------------------------------------------------------------
// bf16 MFMA GEMM: C = act(A · W^T + b1 + b2 + D)
// A: M x K row-major bf16 (lda = K), W: N x K row-major bf16.
// 128x128 tile, BK=32, 256 threads (4 waves, 2x2), wave = 64x64 = 4x4 frags.
// blockIdx.z variants via element strides.
// ---------------------------------------------------------------------------
__device__ __forceinline__ void gload_lds16(const void* g, void* l)
{
    __builtin_amdgcn_global_load_lds(
        (const __attribute__((address_space(1))) unsigned int*)g,
        (__attribute__((address_space(3))) unsigned int*)l, 16, 0, 0);
}

__global__ __launch_bounds__(256) void gemm_mfma(
    const bf16* __restrict__ A, long long sAz,
    const bf16* __restrict__ W, long long sWz,
    const float* __restrict__ b1, long long sb1,
    const float* __restrict__ b2, long long sb2,
    const bf16* __restrict__ D, long long sDz, int ldd,
    float* Cf, long long sCfz,
    bf16* Cb, long long sCbz,
    int M, int N, int K, int ldc, int coloff, int relu)
{
    const int z = blockIdx.z;
    A += (long long)z * sAz;
    W += (long long)z * sWz;
    if (b1) b1 += (long long)z * sb1;
    if (b2) b2 += (long long)z * sb2;
    if (D)  D  += (long long)z * sDz;
    if (Cf) Cf += (long long)z * sCfz;
    if (Cb) Cb += (long long)z * sCbz;

    __shared__ bf16 As[128 * 32];
    __shared__ bf16 Bs[128 * 32];

    const int tid  = threadIdx.x;
    const int wave = tid >> 6;
    const int lane = tid & 63;
    const int wm = wave >> 1;          // 0..1
    const int wn = wave & 1;           // 0..1
    const long long m0 = (long long)blockIdx.x * 128;
    const long long n0 = (long long)blockIdx.y * 128;

    const int srow = tid >> 2;         // 0..63
    const int scol = (tid & 3) * 8;    // bf16 elems within a 32-elem row

    f32x4 acc[4][4] = {};

    const bf16* Abase = A + (m0 + srow) * (long long)K + scol;
    const bf16* Wbase = W + (n0 + srow) * (long long)K + scol;
    const long long K64 = (long long)K * 64;

    const int lrow = (lane >> 4) * 8;  // k-offset for frag reads
    const int frow = lane & 15;        // m/n index within frag

    for (int k0 = 0; k0 < K; k0 += 32) {
        gload_lds16(Abase + k0,        As + tid * 8);
        gload_lds16(Abase + k0 + K64,  As + 2048 + tid * 8);
        gload_lds16(Wbase + k0,        Bs + tid * 8);
        gload_lds16(Wbase + k0 + K64,  Bs + 2048 + tid * 8);
        __syncthreads();

        bf16x8 af[4], bf[4];
#pragma unroll
        for (int i = 0; i < 4; ++i)
            af[i] = *(const bf16x8*)(As + (wm * 64 + i * 16 + frow) * 32 + lrow);
#pragma unroll
        for (int j = 0; j < 4; ++j)
            bf[j] = *(const bf16x8*)(Bs + (wn * 64 + j * 16 + frow) * 32 + lrow);
#pragma unroll
        for (int i = 0; i < 4; ++i)
#pragma unroll
            for (int j = 0; j < 4; ++j)
                acc[i][j] = __builtin_amdgcn_mfma_f32_16x16x32_bf16(af[i], bf[j], acc[i][j], 0, 0, 0);
        __syncthreads();
    }

    // epilogue: C/D frag layout col=lane&15, row=(lane>>4)*4+reg
    const long long mwb = m0 + wm * 64;
    const long long nwb = n0 + wn * 64;
    const int rbase = (lane >> 4) * 4;
    const int lcol = lane & 15;
#pragma unroll
    for (int j = 0; j < 4; ++j) {
        const long long col = nwb + j * 16 + lcol;
        float bias = 0.f;
        if (b1) bias += b1[col];
        if (b2) bias += b2[col];
#pragma unroll
        for (int i = 0; i < 4; ++i) {
            const long long rowb = mwb + i * 16 + rbase;
#pragma unroll
            for (int r = 0; r < 4; ++r) {
                const long long row = rowb + r;
                float v = acc[i][j][r] + bias;
                if (D) v += __bfloat162float(D[row * (long long)ldd + col]);
                if (relu) v = fmaxf(v, 0.f);
                if (Cf) Cf[row * (long long)ldc + coloff + col] = v;
                if (Cb) Cb[row * (long long)ldc + coloff + col] = __float2bfloat16(v);
            }
        }
    }
}

// ---------------------------------------------------------------------------
__device__ __forceinline__ float sigf(float x) { return 1.f / (1.f + expf(-x)); }

// 2*2048*256 threads: d = dir, b = batch, n = hidden idx
__global__ __launch_bounds__(256) void lstm_gates(
    const float* __restrict__ gsrc,   // GBUF fp32 (t>0)
    const bf16* __restrict__ psrc,    // PRE bf16 (t==0)
    float* __restrict__ cbuf,         // (2,2048,256) fp32
    bf16* __restrict__ hout,          // (2,2048,256) bf16
    bf16* __restrict__ lout,          // (16384,512) bf16: fwd 0..255, bwd 256..511
    int t, int first)
{
    const int gid = blockIdx.x * 256 + threadIdx.x;
    const int d = gid >> 19;
    const int r = gid & ((1 << 19) - 1);
    const int b = r >> 8;
    const int n = r & 255;
    const int te = d ? (7 - t) : t;

    float ig, fg, gg, og;
    if (first) {
        const bf16* row = psrc + (size_t)d * 16384 * 1024 + ((size_t)b * 8 + te) * 1024;
        ig = __bfloat162float(row[n]);
        fg = __bfloat162float(row[n + 256]);
        gg = __bfloat162float(row[n + 512]);
        og = __bfloat162float(row[n + 768]);
    } else {
        const float* row = gsrc + (size_t)d * 2048 * 1024 + (size_t)b * 1024;
        ig = row[n]; fg = row[n + 256]; gg = row[n + 512]; og = row[n + 768];
    }
    const float cp = first ? 0.f : cbuf[gid];

    const float c = sigf(fg) * cp + sigf(ig) * tanhf(gg);
    const float h = sigf(og) * tanhf(c);

    cbuf[gid] = c;
    hout[gid] = __float2bfloat16(h);
    lout[((size_t)b * 8 + te) * 512 + d * 256 + n] = __float2bfloat16(h);
}

// one wave per (b, head)
__global__ __launch_bounds__(64) void attn_kernel(
    const float* __restrict__ qkv,   // (16384, 1536) fp32
    bf16* __restrict__ ctx,          // (16384, 512) bf16
    float* __restrict__ colsum)      // (2048, 8, 8)
{
    const int bh = blockIdx.x;
    const int b = bh >> 3;
    const int h = bh & 7;
    const int t = threadIdx.x;

    __shared__ float q[8][64], k[8][64], v[8][64], p[8][8];
    const float* base = qkv + (size_t)b * 8 * 1536 + h * 64;
#pragma unroll
    for (int s = 0; s < 8; ++s) {
        q[s][t] = base[s * 1536 + t];
        k[s][t] = base[s * 1536 + 512 + t];
        v[s][t] = base[s * 1536 + 1024 + t];
    }
    __syncthreads();

    const int qi = t >> 3;
    const int kj = t & 7;
    float sc = 0.f;
#pragma unroll
    for (int d = 0; d < 64; ++d) sc += q[qi][d] * k[kj][d];
    sc *= 0.125f;

    float mx = sc;
    for (int off = 1; off < 8; off <<= 1) mx = fmaxf(mx, __shfl_xor(mx, off));
    const float e = expf(sc - mx);
    float sum = e;
    for (int off = 1; off < 8; off <<= 1) sum += __shfl_xor(sum, off);
    const float P = e / sum;
    p[qi][kj] = P;

    float cs = P;
    for (int off = 8; off < 64; off <<= 1) cs += __shfl_xor(cs, off);
    if (t < 8) colsum[(size_t)bh * 8 + t] = cs;
    __syncthreads();

    bf16* cb = ctx + ((size_t)b * 8 + qi) * 512 + h * 64;
#pragma unroll
    for (int j = 0; j < 8; ++j) {
        const int d = (t & 7) + 8 * j;
        float o = 0.f;
#pragma unroll
        for (int kk = 0; kk < 8; ++kk) o += p[qi][kk] * v[kk][d];
        cb[d] = __float2bfloat16(o);
    }
}

// weights[b,k] = softmax_k( (1/64) * sum_h colsum[b,h,k] )
__global__ __launch_bounds__(64) void weights_kernel(
    const float* __restrict__ colsum, float* __restrict__ wts)
{
    const int t = threadIdx.x;
    const int b = blockIdx.x * 8 + (t >> 3);
    const int kk = t & 7;
    const float* cs = colsum + (size_t)b * 64;
    float s = 0.f;
#pragma unroll
    for (int h = 0; h < 8; ++h) s += cs[h * 8 + kk];
    s *= (1.f / 64.f);
    float mx = s;
    for (int off = 1; off < 8; off <<= 1) mx = fmaxf(mx, __shfl_xor(mx, off));
    const float e = expf(s - mx);
    float sum = e;
    for (int off = 1; off < 8; off <<= 1) sum += __shfl_xor(sum, off);
    wts[(size_t)b * 8 + kk] = e / sum;
}

// summary[b,e] = sum_s aout[b,s,e] * wts[b,s]
__global__ __launch_bounds__(256) void summary_kernel(
    const float* __restrict__ aout, const float* __restrict__ wts,
    float* __restrict__ summ)
{
    const int gid = blockIdx.x * 256 + threadIdx.x;   // 2048*512
    const int b = gid >> 9;
    const int e = gid & 511;
    const float* ab = aout + (size_t)b * 8 * 512 + e;
    const float* wb = wts + (size_t)b * 8;
    float s = 0.f;
#pragma unroll
    for (int t = 0; t < 8; ++t) s += ab[t * 512] * wb[t];
    summ[gid] = s;
}

__global__ __launch_bounds__(256) void transpose_wc1(
    const float* __restrict__ Wc1, float* __restrict__ Wc1T)
{
    const int gid = blockIdx.x * 256 + threadIdx.x;   // 256*513
    const int j = gid / 513;
    const int e = gid % 513;
    Wc1T[(size_t)e * 256 + j] = Wc1[gid];
}

__global__ __launch_bounds__(256) void coherence_kernel(
    const float* __restrict__ summ, const float* __restrict__ Wc1T,
    const float* __restrict__ bc1, const float* __restrict__ Wc2,
    const float* __restrict__ bc2, float* __restrict__ out)
{
    const int b = blockIdx.x;
    const int j = threadIdx.x;
    __shared__ float s[512];
    __shared__ float red[4];
    s[j]       = summ[(size_t)b * 512 + j];
    s[j + 256] = summ[(size_t)b * 512 + 256 + j];
    __syncthreads();

    float hj = bc1[j];
    for (int e = 0; e < 512; ++e) hj += s[e] * Wc1T[(size_t)e * 256 + j];
    hj = fmaxf(hj, 0.f);
    float val = hj * Wc2[j];
    for (int off = 1; off < 64; off <<= 1) val += __shfl_xor(val, off);
    if ((j & 63) == 0) red[j >> 6] = val;
    __syncthreads();
    if (j == 0) {
        const float tot = red[0] + red[1] + red[2] + red[3] + bc2[0];
        const float c = 1.f / (1.f + expf(-tot));
        out[b] = fminf(c, 0.9998f);
    }
}

// ---------------------------------------------------------------------------
extern "C" void kernel_launch(void* const* d_in, const int* in_sizes, int n_in,
                              void* d_out, int out_size, void* d_ws, size_t ws_size,
                              hipStream_t stream)
{
    (void)in_sizes; (void)n_in; (void)out_size; (void)ws_size;

    const float* audio  = (const float*)d_in[0];
    const float* visual = (const float*)d_in[1];
    const float* Wa1 = (const float*)d_in[2];  const float* ba1 = (const float*)d_in[3];
    const float* Wa2 = (const float*)d_in[4];  const float* ba2 = (const float*)d_in[5];
    const float* Wv1 = (const float*)d_in[6];  const float* bv1 = (const float*)d_in[7];
    const float* Wv2 = (const float*)d_in[8];  const float* bv2 = (const float*)d_in[9];
    const float* Wih = (const float*)d_in[10]; const float* Whh = (const float*)d_in[11];
    const float* bih = (const float*)d_in[12]; const float* bhh = (const float*)d_in[13];
    const float* Wqkv = (const float*)d_in[14]; const float* bqkv = (const float*)d_in[15];
    const float* Wo  = (const float*)d_in[16]; const float* bo  = (const float*)d_in[17];
    const float* Wc1 = (const float*)d_in[18]; const float* bc1 = (const float*)d_in[19];
    const float* Wc2 = (const float*)d_in[20]; const float* bc2 = (const float*)d_in[21];

    char* wsb = (char*)d_ws;
    float* out = (float*)d_out;

    bf16* WB    = (bf16*)(wsb + OFF_WB);
    bf16* ABF   = (bf16*)(wsb + OFF_ABF);
    bf16* VBF   = (bf16*)(wsb + OFF_VBF);
    bf16* M1A   = (bf16*)(wsb + OFF_M1A);
    bf16* M1V   = (bf16*)(wsb + OFF_M1V);
    bf16* SEQ   = (bf16*)(wsb + OFF_SEQ);
    bf16* PRE   = (bf16*)(wsb + OFF_PRE);
    float* GBUF = (float*)(wsb + OFF_GBUF);
    bf16* H     = (bf16*)(wsb + OFF_H);
    float* CB   = (float*)(wsb + OFF_CB);
    bf16* LSTM1 = (bf16*)(wsb + OFF_LSTM1);
    bf16* LSTM2 = (bf16*)(wsb + OFF_LSTM2);
    float* QKV  = (float*)(wsb + OFF_QKV);
    bf16* CTX   = (bf16*)(wsb + OFF_CTX);
    float* AOUT = (float*)(wsb + OFF_AOUT);
    float* COLSUM = (float*)(wsb + OFF_COLSUM);
    float* WTS  = (float*)(wsb + OFF_WTS);
    float* SUMM = (float*)(wsb + OFF_SUMM);
    float* WC1T = (float*)(wsb + OFF_WC1T);

    bf16* Wa1b = WB + WB_WA1;  bf16* Wv1b = WB + WB_WV1;
    bf16* Wa2b = WB + WB_WA2;  bf16* Wv2b = WB + WB_WV2;
    bf16* Wihb = WB + WB_WIH;  bf16* Whhb = WB + WB_WHH;
    bf16* Wqkvb = WB + WB_WQKV; bf16* Wob = WB + WB_WO;

    // --- batched convert fp32 -> bf16 ---
    {
        ConvJobs cj;
        const float* srcs[10] = {audio, visual, Wa1, Wa2, Wv1, Wv2, Wih, Whh, Wqkv, Wo};
        bf16* dsts[10] = {ABF, VBF, Wa1b, Wa2b, Wv1b, Wv2b, Wihb, Whhb, Wqkvb, Wob};
        const long long cnt4[10] = {4194304, 4194304, 131072, 32768, 131072, 32768,
                                    524288, 262144, 196608, 65536};
        long long cum = 0;
        for (int i = 0; i < 10; ++i) {
            cj.src[i] = srcs[i]; cj.dst[i] = dsts[i];
            cj.cum[i] = cum; cum += cnt4[i];
        }
        cj.cum[10] = cum;
        hipLaunchKernelGGL(convert_bf16, dim3(2048), dim3(256), 0, stream, cj, cum);
    }

    auto gemm = [&](const bf16* A, long long sAz, const bf16* W, long long sWz,
                    const float* b1, long long sb1, const float* b2, long long sb2,
                    const bf16* D, long long sDz, int ldd,
                    float* Cf, long long sCfz, bf16* Cb, long long sCbz,
                    int M, int N, int K, int ldc, int coloff, int relu, int nz) {
        dim3 grid(M / 128, N / 128, nz);
        hipLaunchKernelGGL(gemm_mfma, grid, dim3(256), 0, stream,
                           A, sAz, W, sWz, b1, sb1, b2, sb2, D, sDz, ldd,
                           Cf, sCfz, Cb, sCbz, M, N, K, ldc, coloff, relu);
    };

    // --- modality MLPs ---
    gemm(ABF, 0, Wa1b, 0, ba1, 0, nullptr, 0, nullptr, 0, 0,
         nullptr, 0, M1A, 0, ROWS, 512, 1024, 512, 0, 1, 1);
    gemm(VBF, 0, Wv1b, 0, bv1, 0, nullptr, 0, nullptr, 0, 0,
         nullptr, 0, M1V, 0, ROWS, 512, 1024, 512, 0, 1, 1);
    gemm(M1A, 0, Wa2b, 0, ba2, 0, nullptr, 0, nullptr, 0, 0,
         nullptr, 0, SEQ, 0, ROWS, 256, 512, 512, 0, 0, 1);
    gemm(M1V, 0, Wv2b, 0, bv2, 0, nullptr, 0, nullptr, 0, 0,
         nullptr, 0, SEQ, 0, ROWS, 256, 512, 512, 256, 0, 1);

    // --- BiLSTM, 2 layers ---
    for (int l = 0; l < 2; ++l) {
        const bf16* xin = (l == 0) ? SEQ : LSTM1;
        bf16* lout      = (l == 0) ? LSTM1 : LSTM2;
        const bf16* Wih_l = Wihb + (size_t)l * 2 * 1024 * 512;
        const bf16* Whh_l = Whhb + (size_t)l * 2 * 1024 * 256;
        const float* bih_l = bih + (size_t)l * 2 * 1024;
        const float* bhh_l = bhh + (size_t)l * 2 * 1024;

        // input projection, both dirs via z -> PRE bf16
        gemm(xin, 0, Wih_l, 1024LL * 512, bih_l, 1024, bhh_l, 1024,
             nullptr, 0, 0, nullptr, 0, PRE, 16384LL * 1024,
             ROWS, 1024, 512, 1024, 0, 0, 2);

        for (int t = 0; t < 8; ++t) {
            if (t > 0) {
                const bf16* Dp = PRE + (size_t)t * 1024;
                const long long sD = 16384LL * 1024 + (long long)(7 - 2 * t) * 1024;
                gemm(H, 2048LL * 256, Whh_l, 1024LL * 256,
                     nullptr, 0, nullptr, 0,
                     Dp, sD, 8192,
                     GBUF, 2048LL * 1024, nullptr, 0,
                     BATCH, 1024, 256, 1024, 0, 0, 2);
            }
            hipLaunchKernelGGL(lstm_gates, dim3(4096), dim3(256), 0, stream,
                               GBUF, PRE, CB, H, lout, t, (int)(t == 0));
        }
    }

    // --- MHA ---
    gemm(LSTM2, 0, Wqkvb, 0, bqkv, 0, nullptr, 0, nullptr, 0, 0,
         QKV, 0, nullptr, 0, ROWS, 1536, 512, 1536, 0, 0, 1);
    hipLaunchKernelGGL(attn_kernel, dim3(BATCH * 8), dim3(64), 0, stream, QKV, CTX, COLSUM);
    hipLaunchKernelGGL(weights_kernel, dim3(BATCH / 8), dim3(64), 0, stream, COLSUM, WTS);
    gemm(CTX, 0, Wob, 0, bo, 0, nullptr, 0, nullptr, 0, 0,
         AOUT, 0, nullptr, 0, ROWS, 512, 512, 512, 0, 0, 1);

    // --- pooling + head ---
    hipLaunchKernelGGL(summary_kernel, dim3(BATCH * 512 / 256), dim3(256), 0, stream,
                       AOUT, WTS, SUMM);
    hipLaunchKernelGGL(transpose_wc1, dim3(513), dim3(256), 0, stream, Wc1, WC1T);
    hipLaunchKernelGGL(coherence_kernel, dim3(BATCH), dim3(256), 0, stream,
                       SUMM, WC1T, bc1, Wc2, bc2, out);
}

// Round 3
// 813.238 us; speedup vs baseline: 3.5177x; 1.3288x over previous
//
#include <hip/hip_runtime.h>
#include <hip/hip_bf16.h>

// ---------------------------------------------------------------------------
// SovarielOmega fused net — round 2: persistent-LSTM recurrence kernel.
// B=2048, S=8, RAW=1024, E=512, H=256, NH=8
// ---------------------------------------------------------------------------

#define ROWS   16384      // B*S
#define BATCH  2048

typedef __bf16 bf16x8 __attribute__((ext_vector_type(8)));
typedef float  f32x4  __attribute__((ext_vector_type(4)));

typedef __hip_bfloat16 bf16;

// ---- workspace layout (byte offsets) ----
#define MB(x) ((size_t)(x) << 20)
static const size_t OFF_WB    = 0;
static const size_t OFF_ABF   = MB(12);
static const size_t OFF_VBF   = MB(44);
static const size_t OFF_M1A   = MB(76);
static const size_t OFF_M1V   = MB(92);
static const size_t OFF_SEQ   = MB(108);
static const size_t OFF_PRE   = MB(124);    // bf16 (2,16384,1024) = 64 MB
static const size_t OFF_LSTM1 = MB(210);
static const size_t OFF_LSTM2 = MB(226);
static const size_t OFF_QKV   = MB(12);     // bf16 (16384,1536) = 50.3 MB (ABF/VBF dead)
static const size_t OFF_CTX   = MB(108);    // reuse SEQ
static const size_t OFF_AOUT  = MB(12);     // fp32 (16384,512) = 33.5 MB (QKV dead)
static const size_t OFF_COLSUM= MB(242);
static const size_t OFF_WTS   = MB(243);
static const size_t OFF_SUMM  = MB(244);
static const size_t OFF_WC1T  = MB(248);

// weight bf16 element offsets within OFF_WB
static const size_t WB_WA1  = 0;
static const size_t WB_WV1  = 524288;
static const size_t WB_WA2  = 1048576;
static const size_t WB_WV2  = 1179648;
static const size_t WB_WIH  = 1310720;
static const size_t WB_WHH  = 3407872;
static const size_t WB_WQKV = 4456448;
static const size_t WB_WO   = 5242880;

// ---------------------------------------------------------------------------
// batched fp32 -> bf16 convert
// ---------------------------------------------------------------------------
struct ConvJobs {
    const float* src[10];
    bf16*        dst[10];
    long long    cum[11];
};

__global__ __launch_bounds__(256) void convert_bf16(ConvJobs jobs, long long total4)
{
    for (long long g = (long long)blockIdx.x * 256 + threadIdx.x; g < total4;
         g += (long long)gridDim.x * 256) {
        int j = 0;
        while (g >= jobs.cum[j + 1]) ++j;
        const long long idx = g - jobs.cum[j];
        const float4 v = ((const float4*)jobs.src[j])[idx];
        union { ushort4 u; bf16 h[4]; } p;
        p.h[0] = __float2bfloat16(v.x);
        p.h[1] = __float2bfloat16(v.y);
        p.h[2] = __float2bfloat16(v.z);
        p.h[3] = __float2bfloat16(v.w);
        ((ushort4*)jobs.dst[j])[idx] = p.u;
    }
}

// ---------------------------------------------------------------------------
__device__ __forceinline__ void gload_lds16(const void* g, void* l)
{
    __builtin_amdgcn_global_load_lds(
        (const __attribute__((address_space(1))) unsigned int*)g,
        (__attribute__((address_space(3))) unsigned int*)l, 16, 0, 0);
}

// ---------------------------------------------------------------------------
// bf16 MFMA GEMM: C = act(A · W^T + b1 + b2 + D)   (128x128 tile, BK=32)
// ---------------------------------------------------------------------------
__global__ __launch_bounds__(256) void gemm_mfma(
    const bf16* __restrict__ A, long long sAz,
    const bf16* __restrict__ W, long long sWz,
    const float* __restrict__ b1, long long sb1,
    const float* __restrict__ b2, long long sb2,
    const bf16* __restrict__ D, long long sDz, int ldd,
    float* Cf, long long sCfz,
    bf16* Cb, long long sCbz,
    int M, int N, int K, int ldc, int coloff, int relu)
{
    const int z = blockIdx.z;
    A += (long long)z * sAz;
    W += (long long)z * sWz;
    if (b1) b1 += (long long)z * sb1;
    if (b2) b2 += (long long)z * sb2;
    if (D)  D  += (long long)z * sDz;
    if (Cf) Cf += (long long)z * sCfz;
    if (Cb) Cb += (long long)z * sCbz;

    __shared__ bf16 As[128 * 32];
    __shared__ bf16 Bs[128 * 32];

    const int tid  = threadIdx.x;
    const int wave = tid >> 6;
    const int lane = tid & 63;
    const int wm = wave >> 1;
    const int wn = wave & 1;
    const long long m0 = (long long)blockIdx.x * 128;
    const long long n0 = (long long)blockIdx.y * 128;

    const int srow = tid >> 2;
    const int scol = (tid & 3) * 8;

    f32x4 acc[4][4] = {};

    const bf16* Abase = A + (m0 + srow) * (long long)K + scol;
    const bf16* Wbase = W + (n0 + srow) * (long long)K + scol;
    const long long K64 = (long long)K * 64;

    const int lrow = (lane >> 4) * 8;
    const int frow = lane & 15;

    for (int k0 = 0; k0 < K; k0 += 32) {
        gload_lds16(Abase + k0,        As + tid * 8);
        gload_lds16(Abase + k0 + K64,  As + 2048 + tid * 8);
        gload_lds16(Wbase + k0,        Bs + tid * 8);
        gload_lds16(Wbase + k0 + K64,  Bs + 2048 + tid * 8);
        __syncthreads();

        bf16x8 af[4], bfv[4];
#pragma unroll
        for (int i = 0; i < 4; ++i)
            af[i] = *(const bf16x8*)(As + (wm * 64 + i * 16 + frow) * 32 + lrow);
#pragma unroll
        for (int j = 0; j < 4; ++j)
            bfv[j] = *(const bf16x8*)(Bs + (wn * 64 + j * 16 + frow) * 32 + lrow);
#pragma unroll
        for (int i = 0; i < 4; ++i)
#pragma unroll
            for (int j = 0; j < 4; ++j)
                acc[i][j] = __builtin_amdgcn_mfma_f32_16x16x32_bf16(af[i], bfv[j], acc[i][j], 0, 0, 0);
        __syncthreads();
    }

    const long long mwb = m0 + wm * 64;
    const long long nwb = n0 + wn * 64;
    const int rbase = (lane >> 4) * 4;
    const int lcol = lane & 15;
#pragma unroll
    for (int j = 0; j < 4; ++j) {
        const long long col = nwb + j * 16 + lcol;
        float bias = 0.f;
        if (b1) bias += b1[col];
        if (b2) bias += b2[col];
#pragma unroll
        for (int i = 0; i < 4; ++i) {
            const long long rowb = mwb + i * 16 + rbase;
#pragma unroll
            for (int r = 0; r < 4; ++r) {
                const long long row = rowb + r;
                float v = acc[i][j][r] + bias;
                if (D) v += __bfloat162float(D[row * (long long)ldd + col]);
                if (relu) v = fmaxf(v, 0.f);
                if (Cf) Cf[row * (long long)ldc + coloff + col] = v;
                if (Cb) Cb[row * (long long)ldc + coloff + col] = __float2bfloat16(v);
            }
        }
    }
}

// ---------------------------------------------------------------------------
__device__ __forceinline__ float sigf(float x) { return 1.f / (1.f + expf(-x)); }

// ---------------------------------------------------------------------------
// Persistent per-layer BiLSTM recurrence.
// Grid 256 x 512 threads. Block owns 16 (dir,batch) rows for all 8 steps.
// Per step: preact = h @ Whh^T (MFMA, Whh streamed from L2 through LDS in
// 8 chunks of 128 rows, XOR-swizzled), gates fused, h kept in LDS.
// PRE: (2,16384,1024) bf16 incl. biases. lout: (16384,512) bf16.
// ---------------------------------------------------------------------------
__global__ __launch_bounds__(512) void lstm_layer(
    const bf16* __restrict__ PRE,
    const bf16* __restrict__ Whh,    // (2,1024,256) bf16, this layer
    bf16* __restrict__ lout)
{
    __shared__ bf16 Bs[128 * 256];          // 64 KB chunk buf; aliased as preact fp32[16][1024]
    __shared__ bf16 Hs[16 * 264];           // h tile, padded stride 264

    float* preact = (float*)Bs;

    const int tid  = threadIdx.x;
    const int wave = tid >> 6;              // 0..7
    const int lane = tid & 63;
    const int frow = lane & 15;
    const int g    = lane >> 4;             // 0..3
    const int rbase = g * 4;

    const int R0  = blockIdx.x * 16;        // global row base (4096 rows = 2 dirs x 2048)
    const int dir = R0 >> 11;
    const int b0  = R0 & 2047;
    const bf16* Wd   = Whh + (size_t)dir * 1024 * 256;
    const bf16* PREd = PRE + (size_t)dir * 16384 * 1024;

    // gates-phase mapping: n = tid&255, row = i*2 + (tid>>8)
    const int gn = tid & 255;
    const int rh = tid >> 8;                // 0/1

    float c_state[8];
#pragma unroll
    for (int i = 0; i < 8; ++i) c_state[i] = 0.f;

    for (int t = 0; t < 8; ++t) {
        if (t > 0) {
            // A-frags: h rows 0..15 x K=256 from Hs
            bf16x8 af[8];
#pragma unroll
            for (int ks = 0; ks < 8; ++ks)
                af[ks] = *(const bf16x8*)(Hs + frow * 264 + ks * 32 + g * 8);

            f32x4 acc[8] = {};
            for (int nb = 0; nb < 8; ++nb) {
                __syncthreads();            // Bs free (prev MFMA / gates reads done)
                // load Whh rows [nb*128, +128) x K=256, XOR-swizzled source
                const bf16* src = Wd + (size_t)nb * 128 * 256;
#pragma unroll
                for (int q = 0; q < 8; ++q) {
                    const int t16 = q * 512 + tid;      // 16B-chunk index 0..4095
                    const int row = t16 >> 5;           // 0..127
                    const int cl  = t16 & 31;
                    const int cg  = cl ^ (row & 7);
                    gload_lds16(src + row * 256 + cg * 8, Bs + t16 * 8);
                }
                __syncthreads();            // drains vmcnt(0) + barrier
                const int lr = wave * 16 + frow;        // this wave's B rows in chunk
#pragma unroll
                for (int ks = 0; ks < 8; ++ks) {
                    const int cgk = ks * 4 + g;
                    const bf16x8 bv = *(const bf16x8*)(Bs + lr * 256 + ((cgk ^ (lr & 7)) * 8));
                    acc[nb] = __builtin_amdgcn_mfma_f32_16x16x32_bf16(af[ks], bv, acc[nb], 0, 0, 0);
                }
            }
            __syncthreads();                // all MFMA reads of Bs done
            // write preact fp32 [16][1024] into Bs region
#pragma unroll
            for (int nb = 0; nb < 8; ++nb) {
                const int col = nb * 128 + wave * 16 + frow;   // lane&15 = col within frag
#pragma unroll
                for (int r = 0; r < 4; ++r)
                    preact[(rbase + r) * 1024 + col] = acc[nb][r];
            }
            __syncthreads();
        }

        // gates phase
        const int te = dir ? (7 - t) : t;
#pragma unroll
        for (int i = 0; i < 8; ++i) {
            const int row = i * 2 + rh;
            const int b = b0 + row;
            const bf16* pr = PREd + ((size_t)b * 8 + te) * 1024;
            float ig = __bfloat162float(pr[gn]);
            float fg = __bfloat162float(pr[gn + 256]);
            float gg = __bfloat162float(pr[gn + 512]);
            float og = __bfloat162float(pr[gn + 768]);
            if (t > 0) {
                ig += preact[row * 1024 + gn];
                fg += preact[row * 1024 + gn + 256];
                gg += preact[row * 1024 + gn + 512];
                og += preact[row * 1024 + gn + 768];
            }
            const float c = sigf(fg) * c_state[i] + sigf(ig) * tanhf(gg);
            const float h = sigf(og) * tanhf(c);
            c_state[i] = c;
            Hs[row * 264 + gn] = __float2bfloat16(h);
            lout[((size_t)b * 8 + te) * 512 + dir * 256 + gn] = __float2bfloat16(h);
        }
        __syncthreads();                    // h ready; preact reads done
    }
}

// ---------------------------------------------------------------------------
// one wave per (b, head); QKV now bf16
__global__ __launch_bounds__(64) void attn_kernel(
    const bf16* __restrict__ qkv,    // (16384, 1536) bf16
    bf16* __restrict__ ctx,          // (16384, 512) bf16
    float* __restrict__ colsum)      // (2048, 8, 8)
{
    const int bh = blockIdx.x;
    const int b = bh >> 3;
    const int h = bh & 7;
    const int t = threadIdx.x;

    __shared__ float q[8][64], k[8][64], v[8][64], p[8][8];
    const bf16* base = qkv + (size_t)b * 8 * 1536 + h * 64;
#pragma unroll
    for (int s = 0; s < 8; ++s) {
        q[s][t] = __bfloat162float(base[s * 1536 + t]);
        k[s][t] = __bfloat162float(base[s * 1536 + 512 + t]);
        v[s][t] = __bfloat162float(base[s * 1536 + 1024 + t]);
    }
    __syncthreads();

    const int qi = t >> 3;
    const int kj = t & 7;
    float sc = 0.f;
#pragma unroll
    for (int d = 0; d < 64; ++d) sc += q[qi][d] * k[kj][d];
    sc *= 0.125f;

    float mx = sc;
    for (int off = 1; off < 8; off <<= 1) mx = fmaxf(mx, __shfl_xor(mx, off));
    const float e = expf(sc - mx);
    float sum = e;
    for (int off = 1; off < 8; off <<= 1) sum += __shfl_xor(sum, off);
    const float P = e / sum;
    p[qi][kj] = P;

    float cs = P;
    for (int off = 8; off < 64; off <<= 1) cs += __shfl_xor(cs, off);
    if (t < 8) colsum[(size_t)bh * 8 + t] = cs;
    __syncthreads();

    bf16* cb = ctx + ((size_t)b * 8 + qi) * 512 + h * 64;
#pragma unroll
    for (int j = 0; j < 8; ++j) {
        const int d = (t & 7) + 8 * j;
        float o = 0.f;
#pragma unroll
        for (int kk = 0; kk < 8; ++kk) o += p[qi][kk] * v[kk][d];
        cb[d] = __float2bfloat16(o);
    }
}

__global__ __launch_bounds__(64) void weights_kernel(
    const float* __restrict__ colsum, float* __restrict__ wts)
{
    const int t = threadIdx.x;
    const int b = blockIdx.x * 8 + (t >> 3);
    const int kk = t & 7;
    const float* cs = colsum + (size_t)b * 64;
    float s = 0.f;
#pragma unroll
    for (int h = 0; h < 8; ++h) s += cs[h * 8 + kk];
    s *= (1.f / 64.f);
    float mx = s;
    for (int off = 1; off < 8; off <<= 1) mx = fmaxf(mx, __shfl_xor(mx, off));
    const float e = expf(s - mx);
    float sum = e;
    for (int off = 1; off < 8; off <<= 1) sum += __shfl_xor(sum, off);
    wts[(size_t)b * 8 + kk] = e / sum;
}

__global__ __launch_bounds__(256) void summary_kernel(
    const float* __restrict__ aout, const float* __restrict__ wts,
    float* __restrict__ summ)
{
    const int gid = blockIdx.x * 256 + threadIdx.x;
    const int b = gid >> 9;
    const int e = gid & 511;
    const float* ab = aout + (size_t)b * 8 * 512 + e;
    const float* wb = wts + (size_t)b * 8;
    float s = 0.f;
#pragma unroll
    for (int t = 0; t < 8; ++t) s += ab[t * 512] * wb[t];
    summ[gid] = s;
}

__global__ __launch_bounds__(256) void transpose_wc1(
    const float* __restrict__ Wc1, float* __restrict__ Wc1T)
{
    const int gid = blockIdx.x * 256 + threadIdx.x;   // 256*513
    const int j = gid / 513;
    const int e = gid % 513;
    Wc1T[(size_t)e * 256 + j] = Wc1[gid];
}

__global__ __launch_bounds__(256) void coherence_kernel(
    const float* __restrict__ summ, const float* __restrict__ Wc1T,
    const float* __restrict__ bc1, const float* __restrict__ Wc2,
    const float* __restrict__ bc2, float* __restrict__ out)
{
    const int b = blockIdx.x;
    const int j = threadIdx.x;
    __shared__ float s[512];
    __shared__ float red[4];
    s[j]       = summ[(size_t)b * 512 + j];
    s[j + 256] = summ[(size_t)b * 512 + 256 + j];
    __syncthreads();

    float hj = bc1[j];
    for (int e = 0; e < 512; ++e) hj += s[e] * Wc1T[(size_t)e * 256 + j];
    hj = fmaxf(hj, 0.f);
    float val = hj * Wc2[j];
    for (int off = 1; off < 64; off <<= 1) val += __shfl_xor(val, off);
    if ((j & 63) == 0) red[j >> 6] = val;
    __syncthreads();
    if (j == 0) {
        const float tot = red[0] + red[1] + red[2] + red[3] + bc2[0];
        const float c = 1.f / (1.f + expf(-tot));
        out[b] = fminf(c, 0.9998f);
    }
}

// ---------------------------------------------------------------------------
extern "C" void kernel_launch(void* const* d_in, const int* in_sizes, int n_in,
                              void* d_out, int out_size, void* d_ws, size_t ws_size,
                              hipStream_t stream)
{
    (void)in_sizes; (void)n_in; (void)out_size; (void)ws_size;

    const float* audio  = (const float*)d_in[0];
    const float* visual = (const float*)d_in[1];
    const float* Wa1 = (const float*)d_in[2];  const float* ba1 = (const float*)d_in[3];
    const float* Wa2 = (const float*)d_in[4];  const float* ba2 = (const float*)d_in[5];
    const float* Wv1 = (const float*)d_in[6];  const float* bv1 = (const float*)d_in[7];
    const float* Wv2 = (const float*)d_in[8];  const float* bv2 = (const float*)d_in[9];
    const float* Wih = (const float*)d_in[10]; const float* Whh = (const float*)d_in[11];
    const float* bih = (const float*)d_in[12]; const float* bhh = (const float*)d_in[13];
    const float* Wqkv = (const float*)d_in[14]; const float* bqkv = (const float*)d_in[15];
    const float* Wo  = (const float*)d_in[16]; const float* bo  = (const float*)d_in[17];
    const float* Wc1 = (const float*)d_in[18]; const float* bc1 = (const float*)d_in[19];
    const float* Wc2 = (const float*)d_in[20]; const float* bc2 = (const float*)d_in[21];

    char* wsb = (char*)d_ws;
    float* out = (float*)d_out;

    bf16* WB    = (bf16*)(wsb + OFF_WB);
    bf16* ABF   = (bf16*)(wsb + OFF_ABF);
    bf16* VBF   = (bf16*)(wsb + OFF_VBF);
    bf16* M1A   = (bf16*)(wsb + OFF_M1A);
    bf16* M1V   = (bf16*)(wsb + OFF_M1V);
    bf16* SEQ   = (bf16*)(wsb + OFF_SEQ);
    bf16* PRE   = (bf16*)(wsb + OFF_PRE);
    bf16* LSTM1 = (bf16*)(wsb + OFF_LSTM1);
    bf16* LSTM2 = (bf16*)(wsb + OFF_LSTM2);
    bf16* QKVB  = (bf16*)(wsb + OFF_QKV);
    bf16* CTX   = (bf16*)(wsb + OFF_CTX);
    float* AOUT = (float*)(wsb + OFF_AOUT);
    float* COLSUM = (float*)(wsb + OFF_COLSUM);
    float* WTS  = (float*)(wsb + OFF_WTS);
    float* SUMM = (float*)(wsb + OFF_SUMM);
    float* WC1T = (float*)(wsb + OFF_WC1T);

    bf16* Wa1b = WB + WB_WA1;  bf16* Wv1b = WB + WB_WV1;
    bf16* Wa2b = WB + WB_WA2;  bf16* Wv2b = WB + WB_WV2;
    bf16* Wihb = WB + WB_WIH;  bf16* Whhb = WB + WB_WHH;
    bf16* Wqkvb = WB + WB_WQKV; bf16* Wob = WB + WB_WO;

    // --- batched convert fp32 -> bf16 ---
    {
        ConvJobs cj;
        const float* srcs[10] = {audio, visual, Wa1, Wa2, Wv1, Wv2, Wih, Whh, Wqkv, Wo};
        bf16* dsts[10] = {ABF, VBF, Wa1b, Wa2b, Wv1b, Wv2b, Wihb, Whhb, Wqkvb, Wob};
        const long long cnt4[10] = {4194304, 4194304, 131072, 32768, 131072, 32768,
                                    524288, 262144, 196608, 65536};
        long long cum = 0;
        for (int i = 0; i < 10; ++i) {
            cj.src[i] = srcs[i]; cj.dst[i] = dsts[i];
            cj.cum[i] = cum; cum += cnt4[i];
        }
        cj.cum[10] = cum;
        hipLaunchKernelGGL(convert_bf16, dim3(2048), dim3(256), 0, stream, cj, cum);
    }

    auto gemm = [&](const bf16* A, long long sAz, const bf16* W, long long sWz,
                    const float* b1, long long sb1, const float* b2, long long sb2,
                    const bf16* D, long long sDz, int ldd,
                    float* Cf, long long sCfz, bf16* Cb, long long sCbz,
                    int M, int N, int K, int ldc, int coloff, int relu, int nz) {
        dim3 grid(M / 128, N / 128, nz);
        hipLaunchKernelGGL(gemm_mfma, grid, dim3(256), 0, stream,
                           A, sAz, W, sWz, b1, sb1, b2, sb2, D, sDz, ldd,
                           Cf, sCfz, Cb, sCbz, M, N, K, ldc, coloff, relu);
    };

    // --- modality MLPs ---
    gemm(ABF, 0, Wa1b, 0, ba1, 0, nullptr, 0, nullptr, 0, 0,
         nullptr, 0, M1A, 0, ROWS, 512, 1024, 512, 0, 1, 1);
    gemm(VBF, 0, Wv1b, 0, bv1, 0, nullptr, 0, nullptr, 0, 0,
         nullptr, 0, M1V, 0, ROWS, 512, 1024, 512, 0, 1, 1);
    gemm(M1A, 0, Wa2b, 0, ba2, 0, nullptr, 0, nullptr, 0, 0,
         nullptr, 0, SEQ, 0, ROWS, 256, 512, 512, 0, 0, 1);
    gemm(M1V, 0, Wv2b, 0, bv2, 0, nullptr, 0, nullptr, 0, 0,
         nullptr, 0, SEQ, 0, ROWS, 256, 512, 512, 256, 0, 1);

    // --- BiLSTM, 2 layers ---
    for (int l = 0; l < 2; ++l) {
        const bf16* xin = (l == 0) ? SEQ : LSTM1;
        bf16* lout      = (l == 0) ? LSTM1 : LSTM2;
        const bf16* Wih_l = Wihb + (size_t)l * 2 * 1024 * 512;
        const bf16* Whh_l = Whhb + (size_t)l * 2 * 1024 * 256;
        const float* bih_l = bih + (size_t)l * 2 * 1024;
        const float* bhh_l = bhh + (size_t)l * 2 * 1024;

        // input projection, both dirs via z -> PRE bf16 (incl. both biases)
        gemm(xin, 0, Wih_l, 1024LL * 512, bih_l, 1024, bhh_l, 1024,
             nullptr, 0, 0, nullptr, 0, PRE, 16384LL * 1024,
             ROWS, 1024, 512, 1024, 0, 0, 2);

        // full recurrence in one persistent kernel
        hipLaunchKernelGGL(lstm_layer, dim3(256), dim3(512), 0, stream,
                           PRE, Whh_l, lout);
    }

    // --- MHA ---
    gemm(LSTM2, 0, Wqkvb, 0, bqkv, 0, nullptr, 0, nullptr, 0, 0,
         nullptr, 0, QKVB, 0, ROWS, 1536, 512, 1536, 0, 0, 1);
    hipLaunchKernelGGL(attn_kernel, dim3(BATCH * 8), dim3(64), 0, stream, QKVB, CTX, COLSUM);
    hipLaunchKernelGGL(weights_kernel, dim3(BATCH / 8), dim3(64), 0, stream, COLSUM, WTS);
    gemm(CTX, 0, Wob, 0, bo, 0, nullptr, 0, nullptr, 0, 0,
         AOUT, 0, nullptr, 0, ROWS, 512, 512, 512, 0, 0, 1);

    // --- pooling + head ---
    hipLaunchKernelGGL(summary_kernel, dim3(BATCH * 512 / 256), dim3(256), 0, stream,
                       AOUT, WTS, SUMM);
    hipLaunchKernelGGL(transpose_wc1, dim3(513), dim3(256), 0, stream, Wc1, WC1T);
    hipLaunchKernelGGL(coherence_kernel, dim3(BATCH), dim3(256), 0, stream,
                       SUMM, WC1T, bc1, Wc2, bc2, out);
}